// Round 5
// baseline (180.805 us; speedup 1.0000x reference)
//
#include <hip/hip_runtime.h>
#include <hip/hip_bf16.h>

typedef __attribute__((ext_vector_type(8))) short bf16x8;
typedef __attribute__((ext_vector_type(4))) float f32x4;
typedef unsigned short u16;

__device__ __forceinline__ u16 f2bf(float f) {  // RNE
  union { float f; unsigned int u; } v; v.f = f;
  return (u16)((v.u + 0x7fffu + ((v.u >> 16) & 1u)) >> 16);
}
// pack two floats -> two bf16 in one u32 (round-half-up; P matrix only)
__device__ __forceinline__ unsigned int pack_bf2(float f0, float f1) {
  union { float f; unsigned int u; } a, b; a.f = f0; b.f = f1;
  return __builtin_amdgcn_perm(b.u + 0x8000u, a.u + 0x8000u, 0x07060302u);
}

#define GLOAD_LDS16(g, l) __builtin_amdgcn_global_load_lds( \
    (const __attribute__((address_space(1))) void*)(g),     \
    (__attribute__((address_space(3))) void*)(l), 16, 0, 0)

// ---------------- fp32 -> bf16 conversion, all tensors in one launch ----------------
__global__ __launch_bounds__(256) void conv_all(const float* __restrict__ x,
                                                const float* __restrict__ wq, const float* __restrict__ wk,
                                                const float* __restrict__ wv, const float* __restrict__ wo,
                                                u16* __restrict__ xb, u16* __restrict__ qo, u16* __restrict__ ko,
                                                u16* __restrict__ vo, u16* __restrict__ oo) {
  int y = blockIdx.y;
  const float* src; u16* dst;
  if (y < 4) { src = x + (size_t)y * 1048576; dst = xb + (size_t)y * 1048576; }
  else if (y == 4) { src = wq; dst = qo; }
  else if (y == 5) { src = wk; dst = ko; }
  else if (y == 6) { src = wv; dst = vo; }
  else { src = wo; dst = oo; }
  int i = (blockIdx.x * 256 + threadIdx.x) * 4;
  float4 v = *(const float4*)(src + i);
  ushort4 o;
  o.x = f2bf(v.x); o.y = f2bf(v.y); o.z = f2bf(v.z); o.w = f2bf(v.w);
  *(ushort4*)(dst + i) = o;
}

// ---------------- shared GEMM mainloop (128M x 128N): acc = A[M,K] @ W[N,K]^T ----------------
// SW=false: acc[mi][ni] D[m=token-sub][n=feat-sub] (classic).
// SW=true : operand-swapped, acc[mi][ni] = D[m=feat-sub][n=token-sub] -> packed epilogue stores.
template <bool SW>
__device__ __forceinline__ void gemm_main(const u16* __restrict__ A, const u16* __restrict__ W,
                                          u16* As, u16* Bs, int m0, int n0, int K,
                                          f32x4 acc[4][4]) {
  int tid = threadIdx.x, wave = tid >> 6, lane = tid & 63;
  int lane15 = lane & 15, quad = lane >> 4;
  int wm = (wave >> 1) * 64, wn = (wave & 1) * 64;
  for (int k0 = 0; k0 < K; k0 += 64) {
    __syncthreads();
#pragma unroll
    for (int i = 0; i < 4; i++) {
      int rbase = wave * 32 + i * 8;
      int rloc = rbase + (lane >> 3);
      int ca = ((lane & 7) ^ (rloc & 7)) * 8;
      GLOAD_LDS16(A + (size_t)(m0 + rloc) * K + k0 + ca, As + rbase * 64);
      GLOAD_LDS16(W + (size_t)(n0 + rloc) * K + k0 + ca, Bs + rbase * 64);
    }
    __syncthreads();
#pragma unroll
    for (int kc = 0; kc < 2; kc++) {
      bf16x8 a[4], b[4];
#pragma unroll
      for (int mi = 0; mi < 4; mi++) {
        int m = wm + mi * 16 + lane15;
        a[mi] = *(const bf16x8*)(As + m * 64 + (((kc * 4 + quad) ^ (m & 7)) * 8));
      }
#pragma unroll
      for (int ni = 0; ni < 4; ni++) {
        int n = wn + ni * 16 + lane15;
        b[ni] = *(const bf16x8*)(Bs + n * 64 + (((kc * 4 + quad) ^ (n & 7)) * 8));
      }
#pragma unroll
      for (int mi = 0; mi < 4; mi++)
#pragma unroll
        for (int ni = 0; ni < 4; ni++)
          acc[mi][ni] = SW ? __builtin_amdgcn_mfma_f32_16x16x32_bf16(b[ni], a[mi], acc[mi][ni], 0, 0, 0)
                           : __builtin_amdgcn_mfma_f32_16x16x32_bf16(a[mi], b[ni], acc[mi][ni], 0, 0, 0);
    }
  }
}

// QKV fused: z=0 -> Q (pre-scaled by softmax scale * log2e), z=1 -> K, z=2 -> V^T [b,h,dh,n]
__global__ __launch_bounds__(256, 3) void gemm_qkv(const u16* __restrict__ xb,
                                                   const u16* __restrict__ wq, const u16* __restrict__ wk,
                                                   const u16* __restrict__ wv,
                                                   u16* __restrict__ Qb, u16* __restrict__ Kb,
                                                   u16* __restrict__ Vtg) {
  __shared__ __align__(16) u16 As[128 * 64];
  __shared__ __align__(16) u16 Bs[128 * 64];
  const int K = 1024;
  int z = blockIdx.z;
  const u16* W = (z == 0) ? wq : (z == 1) ? wk : wv;
  int m0 = blockIdx.x * 128, n0 = blockIdx.y * 128;
  f32x4 acc[4][4];
#pragma unroll
  for (int i = 0; i < 4; i++)
#pragma unroll
    for (int j = 0; j < 4; j++) acc[i][j] = (f32x4){0.f, 0.f, 0.f, 0.f};

  int tid = threadIdx.x, wave = tid >> 6, lane = tid & 63;
  int lane15 = lane & 15, quad = lane >> 4;
  int wm = (wave >> 1) * 64, wn = (wave & 1) * 64;
  const float kQs = 0.022097086912079608f * 1.4426950408889634f;  // 1/sqrt(2048)*log2(e)

  if (z < 2) {
    gemm_main<true>(xb, W, As, Bs, m0, n0, K, acc);
    u16* Out = z ? Kb : Qb;
    float sc = z ? 1.0f : kQs;
    // swapped: acc[mi][ni] -> D[feat = wn+ni*16+quad*4+r][token = wm+mi*16+lane15]
#pragma unroll
    for (int mi = 0; mi < 4; mi++)
#pragma unroll
      for (int ni = 0; ni < 4; ni++) {
        int token = m0 + wm + mi * 16 + lane15;
        int fb = n0 + wn + ni * 16 + quad * 4;
        ushort4 o;
        o.x = f2bf(acc[mi][ni][0] * sc); o.y = f2bf(acc[mi][ni][1] * sc);
        o.z = f2bf(acc[mi][ni][2] * sc); o.w = f2bf(acc[mi][ni][3] * sc);
        *(ushort4*)&Out[(size_t)token * 1024 + fb] = o;
      }
  } else {
    gemm_main<false>(xb, W, As, Bs, m0, n0, K, acc);
    // classic: D[token = wm+mi*16+quad*4+r][feat = wn+ni*16+lane15]; V^T packs along token
#pragma unroll
    for (int mi = 0; mi < 4; mi++)
#pragma unroll
      for (int ni = 0; ni < 4; ni++) {
        int row = m0 + wm + mi * 16 + quad * 4;
        int col = n0 + wn + ni * 16 + lane15;
        int bb = row >> 11, nn = row & 2047;
        ushort4 o;
        o.x = f2bf(acc[mi][ni][0]); o.y = f2bf(acc[mi][ni][1]);
        o.z = f2bf(acc[mi][ni][2]); o.w = f2bf(acc[mi][ni][3]);
        *(ushort4*)&Vtg[(size_t)(bb * 1024 + col) * 2048 + nn] = o;
      }
  }
}

// Output projection, 128M x 64N tiles, operand-swapped -> float4 stores + bias.
__global__ __launch_bounds__(256, 2) void gemm_out(const u16* __restrict__ A, const u16* __restrict__ W,
                                                   float* __restrict__ Of, const float* __restrict__ bias) {
  __shared__ __align__(16) u16 As[128 * 64];
  __shared__ __align__(16) u16 Bs[64 * 64];
  const int K = 1024;
  int m0 = blockIdx.x * 128, n0 = blockIdx.y * 64;
  int tid = threadIdx.x, wave = tid >> 6, lane = tid & 63;
  int lane15 = lane & 15, quad = lane >> 4;
  int wm = (wave >> 1) * 64, wn = (wave & 1) * 32;
  f32x4 acc[4][2];
#pragma unroll
  for (int i = 0; i < 4; i++)
#pragma unroll
    for (int j = 0; j < 2; j++) acc[i][j] = (f32x4){0.f, 0.f, 0.f, 0.f};
  for (int k0 = 0; k0 < K; k0 += 64) {
    __syncthreads();
#pragma unroll
    for (int i = 0; i < 4; i++) {
      int rbase = wave * 32 + i * 8;
      int rloc = rbase + (lane >> 3);
      int ca = ((lane & 7) ^ (rloc & 7)) * 8;
      GLOAD_LDS16(A + (size_t)(m0 + rloc) * K + k0 + ca, As + rbase * 64);
    }
#pragma unroll
    for (int i = 0; i < 2; i++) {
      int rbase = wave * 16 + i * 8;
      int rloc = rbase + (lane >> 3);
      int ca = ((lane & 7) ^ (rloc & 7)) * 8;
      GLOAD_LDS16(W + (size_t)(n0 + rloc) * K + k0 + ca, Bs + rbase * 64);
    }
    __syncthreads();
#pragma unroll
    for (int kc = 0; kc < 2; kc++) {
      bf16x8 a[4], b[2];
#pragma unroll
      for (int mi = 0; mi < 4; mi++) {
        int m = wm + mi * 16 + lane15;
        a[mi] = *(const bf16x8*)(As + m * 64 + (((kc * 4 + quad) ^ (m & 7)) * 8));
      }
#pragma unroll
      for (int ni = 0; ni < 2; ni++) {
        int n = wn + ni * 16 + lane15;
        b[ni] = *(const bf16x8*)(Bs + n * 64 + (((kc * 4 + quad) ^ (n & 7)) * 8));
      }
#pragma unroll
      for (int mi = 0; mi < 4; mi++)
#pragma unroll
        for (int ni = 0; ni < 2; ni++)
          acc[mi][ni] = __builtin_amdgcn_mfma_f32_16x16x32_bf16(b[ni], a[mi], acc[mi][ni], 0, 0, 0);
    }
  }
  // swapped: D[feat = wn+ni*16+quad*4+r][token = wm+mi*16+lane15]
#pragma unroll
  for (int mi = 0; mi < 4; mi++)
#pragma unroll
    for (int ni = 0; ni < 2; ni++) {
      int token = m0 + wm + mi * 16 + lane15;
      int fb = n0 + wn + ni * 16 + quad * 4;
      float4 bb = *(const float4*)&bias[fb];
      float4 o;
      o.x = acc[mi][ni][0] + bb.x; o.y = acc[mi][ni][1] + bb.y;
      o.z = acc[mi][ni][2] + bb.z; o.w = acc[mi][ni][3] + bb.w;
      *(float4*)&Of[(size_t)token * 1024 + fb] = o;
    }
}

// ---------------- flash attention v4: uniform paired strips + KV double-buffer ----------------
// grid (16, 32): block g handles q-strips g and 31-g (64 rows each) of one (b,h).
// Every block does exactly 33 strip-tile units -> dispatch-order-proof balance.
// KV tile 64, double-buffered global_load_lds: loads for t+1 issued right after the
// single per-iter barrier -> whole tile-t compute hides the load latency.
// S^T = K·Q^T per 16-row wave-strip: q = lane15 (per-lane stats), kv = ct*16+quad*4+r.
__global__ __launch_bounds__(256, 2) void attn4(const u16* __restrict__ Q, const u16* __restrict__ Kg,
                                                const u16* __restrict__ Vtg, u16* __restrict__ ctx) {
  __shared__ __align__(16) u16 Ks[2][64 * 64];   // [kv][dh], 16B chunks ^(kv&7)
  __shared__ __align__(16) u16 Vts[2][64 * 64];  // [dh][kv], 16B chunks ^(dh&7)
  __shared__ __align__(16) u16 Ps[128 * 64];     // [prow][kv], 8B units ^((prow&7)<<1); wave-private rows
  int tid = threadIdx.x, wave = tid >> 6, lane = tid & 63;
  int lane15 = lane & 15, quad = lane >> 4;

  int g = blockIdx.x, bh = blockIdx.y;
  int b = bh >> 4, h = bh & 15;
  int tA = g, tB = 31 - g;
  int baseA = g * 64, baseB = (31 - g) * 64;

  // Q B-frags (pre-scaled): B[n=q=lane15][k=dh=quad*8+j]
  bf16x8 qb[2][2];
#pragma unroll
  for (int kc = 0; kc < 2; kc++) {
    qb[0][kc] = *(const bf16x8*)&Q[(size_t)(b * 2048 + baseA + wave * 16 + lane15) * 1024 +
                                   h * 64 + kc * 32 + quad * 8];
    qb[1][kc] = *(const bf16x8*)&Q[(size_t)(b * 2048 + baseB + wave * 16 + lane15) * 1024 +
                                   h * 64 + kc * 32 + quad * 8];
  }

  f32x4 oacc[2][4];  // [strip][dh-tile c4]: D[dh=quad*4+r][q=lane15]
#pragma unroll
  for (int st = 0; st < 2; st++)
#pragma unroll
    for (int c4 = 0; c4 < 4; c4++) oacc[st][c4] = (f32x4){0.f, 0.f, 0.f, 0.f};
  float mrow[2] = {-3.0e38f, -3.0e38f}, lrow[2] = {0.f, 0.f};

  auto stage = [&](int t, int d) {
    int tb = t * 64;
#pragma unroll
    for (int i = 0; i < 2; i++) {
      int rbase = wave * 16 + i * 8;
      int rk = rbase + (lane >> 3);
      int ca = ((lane & 7) ^ (rk & 7)) * 8;
      GLOAD_LDS16(&Kg[(size_t)(b * 2048 + tb + rk) * 1024 + h * 64 + ca], &Ks[d][rbase * 64]);
      GLOAD_LDS16(&Vtg[(size_t)(b * 1024 + h * 64 + rk) * 2048 + tb + ca], &Vts[d][rbase * 64]);
    }
  };

  int sw = (lane15 & 7) << 1;

  auto compute_strip = [&](int st, bool diag, int d) {
    // ---- S^T tile: 64kv x 16q ----
    f32x4 s[4];
#pragma unroll
    for (int ct = 0; ct < 4; ct++) {
      int kr = ct * 16 + lane15;
      const u16* kp = &Ks[d][kr * 64];
      bf16x8 ka0 = *(const bf16x8*)(kp + ((quad ^ (kr & 7)) * 8));
      bf16x8 ka1 = *(const bf16x8*)(kp + (((4 + quad) ^ (kr & 7)) * 8));
      f32x4 z = (f32x4){0.f, 0.f, 0.f, 0.f};
      z = __builtin_amdgcn_mfma_f32_16x16x32_bf16(ka0, qb[st][0], z, 0, 0, 0);
      z = __builtin_amdgcn_mfma_f32_16x16x32_bf16(ka1, qb[st][1], z, 0, 0, 0);
      s[ct] = z;
    }
    if (diag) {
      int ql = wave * 16 + lane15;  // local q within the 64-row strip == local kv scale
#pragma unroll
      for (int ct = 0; ct < 4; ct++)
#pragma unroll
        for (int r = 0; r < 4; r++)
          if (ct * 16 + quad * 4 + r > ql) s[ct][r] = -3.0e38f;
    }
    // ---- online softmax (per-lane q stats; reduce over kv: regs + 2 shfls) ----
    float mx = mrow[st];
#pragma unroll
    for (int ct = 0; ct < 4; ct++)
#pragma unroll
      for (int r = 0; r < 4; r++) mx = fmaxf(mx, s[ct][r]);
    mx = fmaxf(mx, __shfl_xor(mx, 16));
    mx = fmaxf(mx, __shfl_xor(mx, 32));
    float sum = 0.f;
#pragma unroll
    for (int ct = 0; ct < 4; ct++)
#pragma unroll
      for (int r = 0; r < 4; r++) {
        float p = __builtin_amdgcn_exp2f(s[ct][r] - mx);
        s[ct][r] = p; sum += p;
      }
    sum += __shfl_xor(sum, 16);
    sum += __shfl_xor(sum, 32);
    float alpha = __builtin_amdgcn_exp2f(mrow[st] - mx);
    lrow[st] = lrow[st] * alpha + sum;
    mrow[st] = mx;
#pragma unroll
    for (int c4 = 0; c4 < 4; c4++)
#pragma unroll
      for (int r = 0; r < 4; r++) oacc[st][c4][r] *= alpha;
    // ---- P store: packed b64, swizzled 8B units ----
    int prow = st * 64 + wave * 16 + lane15;
#pragma unroll
    for (int ct = 0; ct < 4; ct++) {
      unsigned int lo = pack_bf2(s[ct][0], s[ct][1]);
      unsigned int hi = pack_bf2(s[ct][2], s[ct][3]);
      int u = (ct * 4 + quad) ^ sw;
      *(uint2*)&Ps[prow * 64 + u * 4] = (uint2){lo, hi};
    }
    // ---- O^T += V^T P^T (wave-private P rows; in-order DS pipe) ----
#pragma unroll
    for (int kc = 0; kc < 2; kc++) {
      int up = (kc * 8 + quad * 2) ^ sw;
      bf16x8 pb = *(const bf16x8*)&Ps[prow * 64 + up * 4];
#pragma unroll
      for (int c4 = 0; c4 < 4; c4++) {
        int dh = c4 * 16 + lane15;
        bf16x8 va = *(const bf16x8*)&Vts[d][dh * 64 + (((kc * 4 + quad) ^ (dh & 7)) * 8)];
        oacc[st][c4] = __builtin_amdgcn_mfma_f32_16x16x32_bf16(va, pb, oacc[st][c4], 0, 0, 0);
      }
    }
  };

  stage(0, 0);
  for (int t = 0; t <= tB; ++t) {
    __syncthreads();                       // drains tile-t loads (vmcnt 0) + WAR on buf (t+1)&1
    if (t < tB) stage(t + 1, (t + 1) & 1); // prefetch next tile while computing this one
    int d = t & 1;
    if (t <= tA) compute_strip(0, t == tA, d);
    compute_strip(1, t == tB, d);
  }

  // ---- epilogue: ctx[b, q, h*64+dh]; q = lane15, dh = c4*16+quad*4+r (packed) ----
#pragma unroll
  for (int st = 0; st < 2; st++) {
    float inv = 1.0f / lrow[st];
    int qs = (st ? baseB : baseA) + wave * 16 + lane15;
    size_t off = (size_t)(b * 2048 + qs) * 1024 + h * 64;
#pragma unroll
    for (int c4 = 0; c4 < 4; c4++) {
      ushort4 o;
      o.x = f2bf(oacc[st][c4][0] * inv); o.y = f2bf(oacc[st][c4][1] * inv);
      o.z = f2bf(oacc[st][c4][2] * inv); o.w = f2bf(oacc[st][c4][3] * inv);
      *(ushort4*)&ctx[off + c4 * 16 + quad * 4] = o;
    }
  }
}

extern "C" void kernel_launch(void* const* d_in, const int* in_sizes, int n_in,
                              void* d_out, int out_size, void* d_ws, size_t ws_size,
                              hipStream_t stream) {
  const float* x  = (const float*)d_in[0];
  const float* Wq = (const float*)d_in[1];
  const float* Wk = (const float*)d_in[2];
  const float* Wv = (const float*)d_in[3];
  const float* Wo = (const float*)d_in[4];
  const float* bo = (const float*)d_in[5];
  float* out = (float*)d_out;
  char* ws = (char*)d_ws;
  const size_t MB = 1024 * 1024;
  u16* xb   = (u16*)(ws);
  u16* wqb  = (u16*)(ws +  8 * MB);
  u16* wkb  = (u16*)(ws + 10 * MB);
  u16* wvb  = (u16*)(ws + 12 * MB);
  u16* wob  = (u16*)(ws + 14 * MB);
  u16* Qb   = (u16*)(ws + 16 * MB);
  u16* Kb   = (u16*)(ws + 24 * MB);
  u16* Vtg  = (u16*)(ws + 32 * MB);  // V^T: [b,h,dh,n]
  u16* ctxb = (u16*)(ws + 40 * MB);

  conv_all<<<dim3(1024, 8), 256, 0, stream>>>(x, Wq, Wk, Wv, Wo, xb, wqb, wkb, wvb, wob);
  gemm_qkv<<<dim3(32, 8, 3), 256, 0, stream>>>(xb, wqb, wkb, wvb, Qb, Kb, Vtg);
  attn4<<<dim3(16, 32), 256, 0, stream>>>(Qb, Kb, Vtg, ctxb);
  gemm_out<<<dim3(32, 16), 256, 0, stream>>>(ctxb, wob, out, bo);
}